// Round 9
// baseline (156.785 us; speedup 1.0000x reference)
//
#include <hip/hip_runtime.h>

#define N_NODES 50000
#define D 128
#define N_EDGES 600000
#define BN_EPS 1e-5f
#define NREP 8        // stats replicas (contention spreading)
#define BUCKET 64     // max degree capacity (Binomial(600K,1/50K): P(>64)~0)

#define MLP_BLOCKS 512          // 2 blocks/CU (80KB LDS), persistent
#define MLP_WAVES  (MLP_BLOCKS * 4)
#define N_GROUPS   3125         // 50000 / 16 rows per wave-group

// binned scatter geometry (64-node bins so buckets fit in LDS of the merged
// scatterB+gather kernel)
#define NBINS   782             // bin = dst>>6 (64 nodes/bin), 49999>>6 = 781
#define BINCAP  1024            // mean 767, std 27.7 -> 1024 is ~9 sigma
#define SA_EPB  2048            // edges per bin_a block
#define SA_BLOCKS 293           // ceil(600000/2048)

// fused prep block ranges: featconv | weight-transpose | bin_scatter_a
#define FEATC_BLOCKS 3125   // 800000 / 256
#define WPREP_BLOCKS 128    // 32768 / 256
#define PREP_BLOCKS  (FEATC_BLOCKS + WPREP_BLOCKS + SA_BLOCKS)

typedef __attribute__((ext_vector_type(8))) short short8;
typedef __attribute__((ext_vector_type(4))) float floatx4;

__device__ __forceinline__ unsigned f2bf(float f) {
    unsigned x = __float_as_uint(f);
    return (x + 0x7fffu + ((x >> 16) & 1u)) >> 16;  // RNE
}
__device__ __forceinline__ float bflo(unsigned v) { return __uint_as_float(v << 16); }
__device__ __forceinline__ float bfhi(unsigned v) { return __uint_as_float(v & 0xffff0000u); }

// ---------------------------------------------------------------------------
// Micro-zero: stats (NREP*256) + binCnt (1024). One block -- must precede the
// fused prep kernel (binA's global reservation atomics need binCnt=0).
// ---------------------------------------------------------------------------
__global__ __launch_bounds__(256) void zero_kernel(float* __restrict__ stats) {
    int tid = threadIdx.x;
    #pragma unroll
    for (int i = 0; i < (NREP * 256 + 1024) / 256; ++i)
        stats[i * 256 + tid] = 0.f;
}

// ---------------------------------------------------------------------------
// Fused prep: featconv (fp32->bf16) | weight transpose+convert | binned
// scatter stage A. binA is independent of featconv, so its ~5us hides under
// the featconv tail instead of paying its own serial launch (R9 change).
// binA: block-local LDS histogram over 782 bins, block-aggregated global
// reservation, packed (dst<<16|src) into per-bin runs (R5: -19us vs
// per-edge global atomics).
// ---------------------------------------------------------------------------
__global__ __launch_bounds__(256) void prep_kernel(const float* __restrict__ f,
                            unsigned* __restrict__ fb,
                            const float* __restrict__ W1, const float* __restrict__ W2,
                            unsigned short* __restrict__ Wt1, unsigned short* __restrict__ Wt2,
                            const int* __restrict__ ei,
                            int* __restrict__ binCnt,
                            unsigned* __restrict__ binBuf) {
    int b = blockIdx.x;
    int tid = threadIdx.x;
    if (b < FEATC_BLOCKS) {
        int gid = b * 256 + tid;  // < 800000 exactly
        float4 a = ((const float4*)f)[gid * 2];
        float4 c = ((const float4*)f)[gid * 2 + 1];
        uint4 o;
        o.x = f2bf(a.x) | (f2bf(a.y) << 16);
        o.y = f2bf(a.z) | (f2bf(a.w) << 16);
        o.z = f2bf(c.x) | (f2bf(c.y) << 16);
        o.w = f2bf(c.z) | (f2bf(c.w) << 16);
        ((uint4*)fb)[gid] = o;
    } else if (b < FEATC_BLOCKS + WPREP_BLOCKS) {
        int gid = (b - FEATC_BLOCKS) * 256 + tid;  // < 32768
        int m = gid >> 14;
        int idx = gid & (D * D - 1);
        int k = idx >> 7;
        int n = idx & 127;
        const float* W = m ? W2 : W1;
        unsigned short* Wt = m ? Wt2 : Wt1;
        Wt[n * D + k] = (unsigned short)f2bf(W[k * D + n]);
    } else {
        // ---- bin_scatter_a ----
        __shared__ int hist[NBINS];
        __shared__ int base[NBINS];
        for (int i = tid; i < NBINS; i += 256) hist[i] = 0;
        __syncthreads();

        const int e0 = (b - FEATC_BLOCKS - WPREP_BLOCKS) * SA_EPB;
        const int nE = min(SA_EPB, N_EDGES - e0);

        unsigned pk[8];
        int lp[8];
        int bn_[8];
        #pragma unroll
        for (int k = 0; k < 8; ++k) {
            int idx = tid + k * 256;
            if (idx < nE) {
                int e = e0 + idx;
                unsigned src = (unsigned)ei[e];
                unsigned dst = (unsigned)ei[N_EDGES + e];
                int bb = (int)(dst >> 6);
                pk[k] = (dst << 16) | src;
                bn_[k] = bb;
                lp[k] = atomicAdd(&hist[bb], 1);   // LDS atomic (ds_add_rtn)
            } else {
                bn_[k] = -1;
            }
        }
        __syncthreads();
        for (int bb = tid; bb < NBINS; bb += 256) {
            int h = hist[bb];
            base[bb] = h ? atomicAdd(&binCnt[bb], h) : 0;   // ~725 global atomics/block
        }
        __syncthreads();
        #pragma unroll
        for (int k = 0; k < 8; ++k) {
            if (bn_[k] >= 0) {
                int off = base[bn_[k]] + lp[k];
                if (off < BINCAP)
                    binBuf[bn_[k] * BINCAP + off] = pk[k];
            }
        }
    }
}

// ---------------------------------------------------------------------------
// Merged scatter-B + gather: one block per 64-node bin, 256 threads.
// Phase 1: distribute the bin's ~770 edges into LDS buckets (8KB) via LDS
//   atomics -- buckets never touch global memory (R8: -2.4us vs ssrc
//   round-trip through HBM + extra launch).
// Phase 2: 4 waves x 4 nodes x 4 passes gather h[n] = feat[n] + sum feat[s],
//   indices broadcast-read from LDS, features from global, 8-deep pipeline,
//   coalesced 1KB hb writes per wave. 8.5KB LDS -> 8 blocks/CU = 32 waves/CU
//   (R1's 2-wave/SIMD latency trap does not apply).
// ---------------------------------------------------------------------------
__global__ __launch_bounds__(256) void bucket_gather(const unsigned* __restrict__ binBuf,
                                                     const int* __restrict__ binCnt,
                                                     const uint4* __restrict__ fb4,
                                                     uint4* __restrict__ hb4) {
    __shared__ unsigned short lss[64 * BUCKET];  // 8KB: per-node buckets
    __shared__ int lcnt[64];
    const int tid = threadIdx.x;
    const int b = blockIdx.x;
    if (tid < 64) lcnt[tid] = 0;
    __syncthreads();

    const int E = min(binCnt[b], BINCAP);
    const unsigned* buf = binBuf + b * BINCAP;
    for (int i = tid; i < E; i += 256) {
        unsigned p = buf[i];
        int d6 = (int)(p >> 16) & 63;
        int src = (int)(p & 0xffffu);
        int pos = atomicAdd(&lcnt[d6], 1);       // LDS atomic
        if (pos < BUCKET) lss[d6 * BUCKET + pos] = (unsigned short)src;
    }
    __syncthreads();

    const int lane = tid & 63;
    const int wid = tid >> 6;
    const int quad = lane >> 4;
    const int l16 = lane & 15;

    #pragma unroll
    for (int pass = 0; pass < 4; ++pass) {
        const int nl = pass * 16 + wid * 4 + quad;   // 0..63
        const int node = (b << 6) + nl;
        if (node >= N_NODES) continue;               // only bin 781 tail
        const int deg = min(lcnt[nl], BUCKET);
        const int lbase = nl * BUCKET;

        uint4 own = fb4[node * 16 + l16];
        float a0 = bflo(own.x), a1 = bfhi(own.x);
        float a2 = bflo(own.y), a3 = bfhi(own.y);
        float a4 = bflo(own.z), a5 = bfhi(own.z);
        float a6 = bflo(own.w), a7 = bfhi(own.w);

        int j = 0;
        #define ACC8(v) do { \
            a0 += bflo((v).x); a1 += bfhi((v).x); \
            a2 += bflo((v).y); a3 += bfhi((v).y); \
            a4 += bflo((v).z); a5 += bfhi((v).z); \
            a6 += bflo((v).w); a7 += bfhi((v).w); } while (0)
        for (; j + 7 < deg; j += 8) {
            uint4 sv = *(const uint4*)&lss[lbase + j];   // 8 indices (LDS, broadcast)
            int i0 = sv.x & 0xffff, i1 = sv.x >> 16;
            int i2 = sv.y & 0xffff, i3 = sv.y >> 16;
            int i4 = sv.z & 0xffff, i5 = sv.z >> 16;
            int i6 = sv.w & 0xffff, i7 = sv.w >> 16;
            uint4 v0 = fb4[i0 * 16 + l16];
            uint4 v1 = fb4[i1 * 16 + l16];
            uint4 v2 = fb4[i2 * 16 + l16];
            uint4 v3 = fb4[i3 * 16 + l16];
            uint4 v4 = fb4[i4 * 16 + l16];
            uint4 v5 = fb4[i5 * 16 + l16];
            uint4 v6 = fb4[i6 * 16 + l16];
            uint4 v7 = fb4[i7 * 16 + l16];
            ACC8(v0); ACC8(v1); ACC8(v2); ACC8(v3);
            ACC8(v4); ACC8(v5); ACC8(v6); ACC8(v7);
        }
        if (j + 3 < deg) {
            ushort4 sv = *(const ushort4*)&lss[lbase + j];
            uint4 v0 = fb4[(int)sv.x * 16 + l16];
            uint4 v1 = fb4[(int)sv.y * 16 + l16];
            uint4 v2 = fb4[(int)sv.z * 16 + l16];
            uint4 v3 = fb4[(int)sv.w * 16 + l16];
            ACC8(v0); ACC8(v1); ACC8(v2); ACC8(v3);
            j += 4;
        }
        for (; j < deg; ++j) {
            uint4 v = fb4[(int)lss[lbase + j] * 16 + l16];
            ACC8(v);
        }
        #undef ACC8

        uint4 o;
        o.x = f2bf(a0) | (f2bf(a1) << 16);
        o.y = f2bf(a2) | (f2bf(a3) << 16);
        o.z = f2bf(a4) | (f2bf(a5) << 16);
        o.w = f2bf(a6) | (f2bf(a7) << 16);
        hb4[node * 16 + l16] = o;
    }
}

// ---------------------------------------------------------------------------
// Persistent-wave fused MLP (R5 structure): per-group compute, both groups'
// A fragments prefetched up front. R7: B-fragment sharing null -- reverted.
// R2/R3: grid-barrier + in-kernel BN costs +23us -- keep split. Prev R13:
// B from global +12us -- keep LDS B.
// ---------------------------------------------------------------------------
__global__ __launch_bounds__(256) void mlp_kernel(
    const unsigned short* __restrict__ A,
    const unsigned short* __restrict__ Bt1, const unsigned short* __restrict__ Bt2,
    const float* __restrict__ bias1, const float* __restrict__ bias2,
    unsigned short* __restrict__ yb, float* __restrict__ stats)
{
    __shared__ unsigned short B1lds[128 * 128];   // 32KB
    __shared__ unsigned short B2lds[128 * 128];   // 32KB
    __shared__ unsigned short Xch[4 * 16 * 128];  // 16KB: per-wave h1 exchange

    const int tid = threadIdx.x;

    #pragma unroll
    for (int i = 0; i < 8; ++i) {  // B1 + B2: 2048 16B granules each
        int c = tid + i * 256;
        int row = c >> 4;
        int g = c & 15;
        int dst = row * 128 + (g ^ (row & 15)) * 8;
        int src = row * 128 + g * 8;
        *(uint4*)&B1lds[dst] = *(const uint4*)&Bt1[src];
        *(uint4*)&B2lds[dst] = *(const uint4*)&Bt2[src];
    }
    __syncthreads();  // the only block-wide barrier before the flush

    const int lane = tid & 63;
    const int wid = tid >> 6;
    const int l15 = lane & 15;
    const int quad = lane >> 4;
    unsigned short* X = &Xch[wid * 2048];  // wave-private [16][128]

    float bs1[8], bs2[8];
    #pragma unroll
    for (int n = 0; n < 8; ++n) {
        bs1[n] = bias1[n * 16 + l15];
        bs2[n] = bias2[n * 16 + l15];
    }

    float s[8], q[8];
    #pragma unroll
    for (int n = 0; n < 8; ++n) { s[n] = 0.f; q[n] = 0.f; }

    const int gw = blockIdx.x * 4 + wid;   // global wave id, 0..2047
    const int g1 = gw + MLP_WAVES;
    const bool has1 = (g1 < N_GROUPS);     // wave-uniform
    const int g1m = has1 ? g1 : gw;        // safe address for dead prefetch

    // ---- prefetch BOTH groups' A fragments up front ----
    short8 afA[4], afB[4];
    #pragma unroll
    for (int kc = 0; kc < 4; ++kc)
        afA[kc] = *(const short8*)&A[(gw * 16 + l15) * 128 + kc * 32 + quad * 8];
    #pragma unroll
    for (int kc = 0; kc < 4; ++kc)
        afB[kc] = *(const short8*)&A[(g1m * 16 + l15) * 128 + kc * 32 + quad * 8];

    auto compute = [&](int rowBase, short8* af) {
        // ---- GEMM1 ----
        floatx4 acc[8];
        #pragma unroll
        for (int n = 0; n < 8; ++n) acc[n] = (floatx4){0.f, 0.f, 0.f, 0.f};
        #pragma unroll
        for (int kc = 0; kc < 4; ++kc) {
            int ga = (kc * 4 + quad) ^ l15;
            #pragma unroll
            for (int n = 0; n < 8; ++n) {
                short8 bf = *(const short8*)&B1lds[(n * 16 + l15) * 128 + ga * 8];
                acc[n] = __builtin_amdgcn_mfma_f32_16x16x32_bf16(af[kc], bf, acc[n], 0, 0, 0);
            }
        }

        // ---- h1 C-layout -> A-layout via wave-private LDS (no barrier) ----
        #pragma unroll
        for (int n = 0; n < 8; ++n) {
            int col = n * 16 + l15;
            int gg = col >> 3;
            int o7 = col & 7;
            #pragma unroll
            for (int r = 0; r < 4; ++r) {
                int rl = quad * 4 + r;
                float v = fmaxf(acc[n][r] + bs1[n], 0.f);
                X[rl * 128 + ((gg ^ rl) * 8) + o7] = (unsigned short)f2bf(v);
            }
        }
        short8 hf[4];
        #pragma unroll
        for (int kc = 0; kc < 4; ++kc)
            hf[kc] = *(const short8*)&X[l15 * 128 + (((kc * 4 + quad) ^ l15) * 8)];

        // ---- GEMM2 ----
        #pragma unroll
        for (int n = 0; n < 8; ++n) acc[n] = (floatx4){0.f, 0.f, 0.f, 0.f};
        #pragma unroll
        for (int kc = 0; kc < 4; ++kc) {
            int ga = (kc * 4 + quad) ^ l15;
            #pragma unroll
            for (int n = 0; n < 8; ++n) {
                short8 bf = *(const short8*)&B2lds[(n * 16 + l15) * 128 + ga * 8];
                acc[n] = __builtin_amdgcn_mfma_f32_16x16x32_bf16(hf[kc], bf, acc[n], 0, 0, 0);
            }
        }

        // ---- ReLU + y store + BN partials in registers ----
        #pragma unroll
        for (int n = 0; n < 8; ++n) {
            int col = n * 16 + l15;
            #pragma unroll
            for (int r = 0; r < 4; ++r) {
                int row = rowBase + quad * 4 + r;
                float v = fmaxf(acc[n][r] + bs2[n], 0.f);
                yb[row * 128 + col] = (unsigned short)f2bf(v);
                s[n] += v;
                q[n] += v * v;
            }
        }
    };

    compute(gw * 16, afA);
    if (has1) compute(g1 * 16, afB);

    // ---- flush BN partials: quad-reduce, block-reduce, one atomic set ----
    #pragma unroll
    for (int n = 0; n < 8; ++n) {
        s[n] += __shfl_xor(s[n], 16);
        s[n] += __shfl_xor(s[n], 32);
        q[n] += __shfl_xor(q[n], 16);
        q[n] += __shfl_xor(q[n], 32);
    }
    __syncthreads();  // all waves done with B1lds; reuse as scratch
    float* red = (float*)B1lds;  // [0..511]=sums [512..1023]=sqs
    if (lane < 16) {
        #pragma unroll
        for (int n = 0; n < 8; ++n) {
            red[wid * 128 + n * 16 + lane] = s[n];
            red[512 + wid * 128 + n * 16 + lane] = q[n];
        }
    }
    __syncthreads();
    float* myStats = stats + (blockIdx.x & (NREP - 1)) * 256;
    if (tid < 128) {
        float ss = 0.f, qq = 0.f;
        #pragma unroll
        for (int w = 0; w < 4; ++w) {
            ss += red[w * 128 + tid];
            qq += red[512 + w * 128 + tid];
        }
        atomicAdd(&myStats[tid], ss);
        atomicAdd(&myStats[128 + tid], qq);
    }
}

// ---------------------------------------------------------------------------
// BatchNorm apply: reduce the NREP stats replicas in-block, precompute
// per-column scale/shift, then o = y*scale + shift. 4 uint4s per thread.
// ---------------------------------------------------------------------------
__global__ __launch_bounds__(256) void bn_kernel(const uint4* __restrict__ yb4,
                                                 float* __restrict__ out,
                                                 const float* __restrict__ stats,
                                                 const float* __restrict__ gamma,
                                                 const float* __restrict__ beta)
{
    __shared__ float red[256];
    __shared__ float sc[128], sh[128];
    int tid = threadIdx.x;

    float acc = 0.f;
    #pragma unroll
    for (int r = 0; r < NREP; ++r) acc += stats[r * 256 + tid];
    red[tid] = acc;
    __syncthreads();
    if (tid < 128) {
        const float inv_n = 1.0f / (float)N_NODES;
        float m = red[tid] * inv_n;
        float var = red[128 + tid] * inv_n - m * m;
        float scale = gamma[tid] * rsqrtf(var + BN_EPS);
        sc[tid] = scale;
        sh[tid] = beta[tid] - m * scale;
    }
    __syncthreads();

    const int n8 = N_NODES * D / 8;  // 800000 uint4s
    int base = (blockIdx.x * 256 + tid) * 4;
    #pragma unroll
    for (int i = 0; i < 4; ++i) {
        int idx = base + i;
        if (idx >= n8) break;
        int c0 = (idx << 3) & 127;
        uint4 v = yb4[idx];
        float4 o0, o1;
        o0.x = bflo(v.x) * sc[c0 + 0] + sh[c0 + 0];
        o0.y = bfhi(v.x) * sc[c0 + 1] + sh[c0 + 1];
        o0.z = bflo(v.y) * sc[c0 + 2] + sh[c0 + 2];
        o0.w = bfhi(v.y) * sc[c0 + 3] + sh[c0 + 3];
        o1.x = bflo(v.z) * sc[c0 + 4] + sh[c0 + 4];
        o1.y = bfhi(v.z) * sc[c0 + 5] + sh[c0 + 5];
        o1.z = bflo(v.w) * sc[c0 + 6] + sh[c0 + 6];
        o1.w = bfhi(v.w) * sc[c0 + 7] + sh[c0 + 7];
        ((float4*)out)[idx * 2] = o0;
        ((float4*)out)[idx * 2 + 1] = o1;
    }
}

// ---------------------------------------------------------------------------
extern "C" void kernel_launch(void* const* d_in, const int* in_sizes, int n_in,
                              void* d_out, int out_size, void* d_ws, size_t ws_size,
                              hipStream_t stream) {
    const float* feature = (const float*)d_in[0];
    const int*   ei      = (const int*)d_in[1];
    const float* W1      = (const float*)d_in[2];
    const float* b1      = (const float*)d_in[3];
    const float* W2      = (const float*)d_in[4];
    const float* b2      = (const float*)d_in[5];
    const float* gamma   = (const float*)d_in[6];
    const float* beta    = (const float*)d_in[7];
    float* out = (float*)d_out;

    unsigned*       featb   = (unsigned*)d_ws;                        // 12.8 MB
    unsigned*       hb      = featb + N_NODES * 64;                   // 12.8 MB
    unsigned*       yb32    = hb + N_NODES * 64;                      // 12.8 MB
    unsigned short* Wt1     = (unsigned short*)(yb32 + N_NODES * 64); // 32 KB
    unsigned short* Wt2     = Wt1 + D * D;                            // 32 KB
    float*          stats   = (float*)(Wt2 + D * D);                  // 8 KB (NREP=8)
    int*            binCnt  = (int*)(stats + NREP * 256);             // 4 KB
    unsigned*       binBuf  = (unsigned*)(binCnt + 1024);             // 3.2 MB bin runs
    unsigned short* yb      = (unsigned short*)yb32;

    zero_kernel<<<1, 256, 0, stream>>>(stats);   // stats + binCnt
    prep_kernel<<<PREP_BLOCKS, 256, 0, stream>>>(
        feature, featb, W1, W2, Wt1, Wt2, ei, binCnt, binBuf);
    bucket_gather<<<NBINS, 256, 0, stream>>>(
        binBuf, binCnt, (const uint4*)featb, (uint4*)hb);
    mlp_kernel<<<MLP_BLOCKS, 256, 0, stream>>>(
        (const unsigned short*)hb, Wt1, Wt2, b1, b2, yb, stats);
    bn_kernel<<<(N_NODES * D / 8 / 4 + 255) / 256, 256, 0, stream>>>(
        (const uint4*)yb, out, stats, gamma, beta);
}

// Round 10
// 155.221 us; speedup vs baseline: 1.0101x; 1.0101x over previous
//
#include <hip/hip_runtime.h>

#define N_NODES 50000
#define D 128
#define N_EDGES 600000
#define BN_EPS 1e-5f
#define NREP 8        // stats replicas (contention spreading)
#define BUCKET 64     // max degree capacity (Binomial(600K,1/50K): P(>64)~0)

#define MLP_BLOCKS 512          // 2 blocks/CU (80KB LDS), persistent
#define MLP_WAVES  (MLP_BLOCKS * 4)
#define N_GROUPS   3125         // 50000 / 16 rows per wave-group

// binned scatter geometry (64-node bins so buckets fit in LDS of the merged
// scatterB+gather kernel)
#define NBINS   782             // bin = dst>>6 (64 nodes/bin), 49999>>6 = 781
#define BINCAP  1024            // mean 767, std 27.7 -> 1024 is ~9 sigma
#define SA_EPB  2048            // edges per bin_a block
#define SA_BLOCKS 293           // ceil(600000/2048)

// prep_kernel block ranges
#define FEATC_BLOCKS 3125   // 800000 / 256
#define WPREP_BLOCKS 128    // 32768 / 256
#define ZERO_BLOCKS  12     // ceil((NREP*256 + 1024)/256): stats + binCnt

typedef __attribute__((ext_vector_type(8))) short short8;
typedef __attribute__((ext_vector_type(4))) float floatx4;

__device__ __forceinline__ unsigned f2bf(float f) {
    unsigned x = __float_as_uint(f);
    return (x + 0x7fffu + ((x >> 16) & 1u)) >> 16;  // RNE
}
__device__ __forceinline__ float bflo(unsigned v) { return __uint_as_float(v << 16); }
__device__ __forceinline__ float bfhi(unsigned v) { return __uint_as_float(v & 0xffff0000u); }

// ---------------------------------------------------------------------------
// Fused prep: featconv (fp32->bf16), weight transpose+convert, zero
// stats+binCnt. (R9 post-mortem: fusing bin_scatter_a in here was null --
// the 3125 featconv blocks saturate the GPU, so appended ranges serialize
// anyway. This is the proven R8 structure, 155.3us.)
// ---------------------------------------------------------------------------
__global__ void prep_kernel(const float* __restrict__ f, unsigned* __restrict__ fb,
                            const float* __restrict__ W1, const float* __restrict__ W2,
                            unsigned short* __restrict__ Wt1, unsigned short* __restrict__ Wt2,
                            float* __restrict__ stats) {
    int b = blockIdx.x;
    int tid = threadIdx.x;
    if (b < FEATC_BLOCKS) {
        int gid = b * 256 + tid;  // < 800000 exactly
        float4 a = ((const float4*)f)[gid * 2];
        float4 c = ((const float4*)f)[gid * 2 + 1];
        uint4 o;
        o.x = f2bf(a.x) | (f2bf(a.y) << 16);
        o.y = f2bf(a.z) | (f2bf(a.w) << 16);
        o.z = f2bf(c.x) | (f2bf(c.y) << 16);
        o.w = f2bf(c.z) | (f2bf(c.w) << 16);
        ((uint4*)fb)[gid] = o;
    } else if (b < FEATC_BLOCKS + WPREP_BLOCKS) {
        int gid = (b - FEATC_BLOCKS) * 256 + tid;  // < 32768
        int m = gid >> 14;
        int idx = gid & (D * D - 1);
        int k = idx >> 7;
        int n = idx & 127;
        const float* W = m ? W2 : W1;
        unsigned short* Wt = m ? Wt2 : Wt1;
        Wt[n * D + k] = (unsigned short)f2bf(W[k * D + n]);
    } else {
        int sid = (b - FEATC_BLOCKS - WPREP_BLOCKS) * 256 + tid;
        if (sid < NREP * 256 + 1024) stats[sid] = 0.f;  // stats + binCnt
    }
}

// ---------------------------------------------------------------------------
// Binned scatter stage A: block-local LDS histogram over 782 bins,
// block-aggregated global reservation, packed (dst<<16|src) into per-bin
// runs. (R5: binned scatter -19us vs per-edge global atomics.)
// ---------------------------------------------------------------------------
__global__ __launch_bounds__(256) void bin_scatter_a(const int* __restrict__ ei,
                                                     int* __restrict__ binCnt,
                                                     unsigned* __restrict__ binBuf) {
    __shared__ int hist[NBINS];
    __shared__ int base[NBINS];
    const int tid = threadIdx.x;
    for (int i = tid; i < NBINS; i += 256) hist[i] = 0;
    __syncthreads();

    const int e0 = blockIdx.x * SA_EPB;
    const int nE = min(SA_EPB, N_EDGES - e0);

    unsigned pk[8];
    int lp[8];
    int bn_[8];
    #pragma unroll
    for (int k = 0; k < 8; ++k) {
        int idx = tid + k * 256;
        if (idx < nE) {
            int e = e0 + idx;
            unsigned src = (unsigned)ei[e];
            unsigned dst = (unsigned)ei[N_EDGES + e];
            int bb = (int)(dst >> 6);
            pk[k] = (dst << 16) | src;
            bn_[k] = bb;
            lp[k] = atomicAdd(&hist[bb], 1);   // LDS atomic (ds_add_rtn)
        } else {
            bn_[k] = -1;
        }
    }
    __syncthreads();
    for (int bb = tid; bb < NBINS; bb += 256) {
        int h = hist[bb];
        base[bb] = h ? atomicAdd(&binCnt[bb], h) : 0;   // ~725 global atomics/block
    }
    __syncthreads();
    #pragma unroll
    for (int k = 0; k < 8; ++k) {
        if (bn_[k] >= 0) {
            int off = base[bn_[k]] + lp[k];
            if (off < BINCAP)
                binBuf[bn_[k] * BINCAP + off] = pk[k];
        }
    }
}

// ---------------------------------------------------------------------------
// Merged scatter-B + gather: one block per 64-node bin, 256 threads.
// Phase 1: distribute the bin's ~770 edges into LDS buckets (8KB) via LDS
//   atomics -- buckets never touch global memory (R8: -2.4us vs ssrc
//   round-trip through HBM + extra launch).
// Phase 2: 4 waves x 4 nodes x 4 passes gather h[n] = feat[n] + sum feat[s],
//   indices broadcast-read from LDS, features from global, 8-deep pipeline,
//   coalesced 1KB hb writes per wave. 8.5KB LDS -> 8 blocks/CU = 32 waves/CU
//   (R1's 2-wave/SIMD latency trap does not apply).
// ---------------------------------------------------------------------------
__global__ __launch_bounds__(256) void bucket_gather(const unsigned* __restrict__ binBuf,
                                                     const int* __restrict__ binCnt,
                                                     const uint4* __restrict__ fb4,
                                                     uint4* __restrict__ hb4) {
    __shared__ unsigned short lss[64 * BUCKET];  // 8KB: per-node buckets
    __shared__ int lcnt[64];
    const int tid = threadIdx.x;
    const int b = blockIdx.x;
    if (tid < 64) lcnt[tid] = 0;
    __syncthreads();

    const int E = min(binCnt[b], BINCAP);
    const unsigned* buf = binBuf + b * BINCAP;
    for (int i = tid; i < E; i += 256) {
        unsigned p = buf[i];
        int d6 = (int)(p >> 16) & 63;
        int src = (int)(p & 0xffffu);
        int pos = atomicAdd(&lcnt[d6], 1);       // LDS atomic
        if (pos < BUCKET) lss[d6 * BUCKET + pos] = (unsigned short)src;
    }
    __syncthreads();

    const int lane = tid & 63;
    const int wid = tid >> 6;
    const int quad = lane >> 4;
    const int l16 = lane & 15;

    #pragma unroll
    for (int pass = 0; pass < 4; ++pass) {
        const int nl = pass * 16 + wid * 4 + quad;   // 0..63
        const int node = (b << 6) + nl;
        if (node >= N_NODES) continue;               // only bin 781 tail
        const int deg = min(lcnt[nl], BUCKET);
        const int lbase = nl * BUCKET;

        uint4 own = fb4[node * 16 + l16];
        float a0 = bflo(own.x), a1 = bfhi(own.x);
        float a2 = bflo(own.y), a3 = bfhi(own.y);
        float a4 = bflo(own.z), a5 = bfhi(own.z);
        float a6 = bflo(own.w), a7 = bfhi(own.w);

        int j = 0;
        #define ACC8(v) do { \
            a0 += bflo((v).x); a1 += bfhi((v).x); \
            a2 += bflo((v).y); a3 += bfhi((v).y); \
            a4 += bflo((v).z); a5 += bfhi((v).z); \
            a6 += bflo((v).w); a7 += bfhi((v).w); } while (0)
        for (; j + 7 < deg; j += 8) {
            uint4 sv = *(const uint4*)&lss[lbase + j];   // 8 indices (LDS, broadcast)
            int i0 = sv.x & 0xffff, i1 = sv.x >> 16;
            int i2 = sv.y & 0xffff, i3 = sv.y >> 16;
            int i4 = sv.z & 0xffff, i5 = sv.z >> 16;
            int i6 = sv.w & 0xffff, i7 = sv.w >> 16;
            uint4 v0 = fb4[i0 * 16 + l16];
            uint4 v1 = fb4[i1 * 16 + l16];
            uint4 v2 = fb4[i2 * 16 + l16];
            uint4 v3 = fb4[i3 * 16 + l16];
            uint4 v4 = fb4[i4 * 16 + l16];
            uint4 v5 = fb4[i5 * 16 + l16];
            uint4 v6 = fb4[i6 * 16 + l16];
            uint4 v7 = fb4[i7 * 16 + l16];
            ACC8(v0); ACC8(v1); ACC8(v2); ACC8(v3);
            ACC8(v4); ACC8(v5); ACC8(v6); ACC8(v7);
        }
        if (j + 3 < deg) {
            ushort4 sv = *(const ushort4*)&lss[lbase + j];
            uint4 v0 = fb4[(int)sv.x * 16 + l16];
            uint4 v1 = fb4[(int)sv.y * 16 + l16];
            uint4 v2 = fb4[(int)sv.z * 16 + l16];
            uint4 v3 = fb4[(int)sv.w * 16 + l16];
            ACC8(v0); ACC8(v1); ACC8(v2); ACC8(v3);
            j += 4;
        }
        for (; j < deg; ++j) {
            uint4 v = fb4[(int)lss[lbase + j] * 16 + l16];
            ACC8(v);
        }
        #undef ACC8

        uint4 o;
        o.x = f2bf(a0) | (f2bf(a1) << 16);
        o.y = f2bf(a2) | (f2bf(a3) << 16);
        o.z = f2bf(a4) | (f2bf(a5) << 16);
        o.w = f2bf(a6) | (f2bf(a7) << 16);
        hb4[node * 16 + l16] = o;
    }
}

// ---------------------------------------------------------------------------
// Persistent-wave fused MLP (R5 structure): per-group compute, both groups'
// A fragments prefetched up front. R7: B-fragment sharing null -- reverted.
// R2/R3: grid-barrier + in-kernel BN costs +23us -- keep split. Prev R13:
// B from global +12us -- keep LDS B.
// ---------------------------------------------------------------------------
__global__ __launch_bounds__(256) void mlp_kernel(
    const unsigned short* __restrict__ A,
    const unsigned short* __restrict__ Bt1, const unsigned short* __restrict__ Bt2,
    const float* __restrict__ bias1, const float* __restrict__ bias2,
    unsigned short* __restrict__ yb, float* __restrict__ stats)
{
    __shared__ unsigned short B1lds[128 * 128];   // 32KB
    __shared__ unsigned short B2lds[128 * 128];   // 32KB
    __shared__ unsigned short Xch[4 * 16 * 128];  // 16KB: per-wave h1 exchange

    const int tid = threadIdx.x;

    #pragma unroll
    for (int i = 0; i < 8; ++i) {  // B1 + B2: 2048 16B granules each
        int c = tid + i * 256;
        int row = c >> 4;
        int g = c & 15;
        int dst = row * 128 + (g ^ (row & 15)) * 8;
        int src = row * 128 + g * 8;
        *(uint4*)&B1lds[dst] = *(const uint4*)&Bt1[src];
        *(uint4*)&B2lds[dst] = *(const uint4*)&Bt2[src];
    }
    __syncthreads();  // the only block-wide barrier before the flush

    const int lane = tid & 63;
    const int wid = tid >> 6;
    const int l15 = lane & 15;
    const int quad = lane >> 4;
    unsigned short* X = &Xch[wid * 2048];  // wave-private [16][128]

    float bs1[8], bs2[8];
    #pragma unroll
    for (int n = 0; n < 8; ++n) {
        bs1[n] = bias1[n * 16 + l15];
        bs2[n] = bias2[n * 16 + l15];
    }

    float s[8], q[8];
    #pragma unroll
    for (int n = 0; n < 8; ++n) { s[n] = 0.f; q[n] = 0.f; }

    const int gw = blockIdx.x * 4 + wid;   // global wave id, 0..2047
    const int g1 = gw + MLP_WAVES;
    const bool has1 = (g1 < N_GROUPS);     // wave-uniform
    const int g1m = has1 ? g1 : gw;        // safe address for dead prefetch

    // ---- prefetch BOTH groups' A fragments up front ----
    short8 afA[4], afB[4];
    #pragma unroll
    for (int kc = 0; kc < 4; ++kc)
        afA[kc] = *(const short8*)&A[(gw * 16 + l15) * 128 + kc * 32 + quad * 8];
    #pragma unroll
    for (int kc = 0; kc < 4; ++kc)
        afB[kc] = *(const short8*)&A[(g1m * 16 + l15) * 128 + kc * 32 + quad * 8];

    auto compute = [&](int rowBase, short8* af) {
        // ---- GEMM1 ----
        floatx4 acc[8];
        #pragma unroll
        for (int n = 0; n < 8; ++n) acc[n] = (floatx4){0.f, 0.f, 0.f, 0.f};
        #pragma unroll
        for (int kc = 0; kc < 4; ++kc) {
            int ga = (kc * 4 + quad) ^ l15;
            #pragma unroll
            for (int n = 0; n < 8; ++n) {
                short8 bf = *(const short8*)&B1lds[(n * 16 + l15) * 128 + ga * 8];
                acc[n] = __builtin_amdgcn_mfma_f32_16x16x32_bf16(af[kc], bf, acc[n], 0, 0, 0);
            }
        }

        // ---- h1 C-layout -> A-layout via wave-private LDS (no barrier) ----
        #pragma unroll
        for (int n = 0; n < 8; ++n) {
            int col = n * 16 + l15;
            int gg = col >> 3;
            int o7 = col & 7;
            #pragma unroll
            for (int r = 0; r < 4; ++r) {
                int rl = quad * 4 + r;
                float v = fmaxf(acc[n][r] + bs1[n], 0.f);
                X[rl * 128 + ((gg ^ rl) * 8) + o7] = (unsigned short)f2bf(v);
            }
        }
        short8 hf[4];
        #pragma unroll
        for (int kc = 0; kc < 4; ++kc)
            hf[kc] = *(const short8*)&X[l15 * 128 + (((kc * 4 + quad) ^ l15) * 8)];

        // ---- GEMM2 ----
        #pragma unroll
        for (int n = 0; n < 8; ++n) acc[n] = (floatx4){0.f, 0.f, 0.f, 0.f};
        #pragma unroll
        for (int kc = 0; kc < 4; ++kc) {
            int ga = (kc * 4 + quad) ^ l15;
            #pragma unroll
            for (int n = 0; n < 8; ++n) {
                short8 bf = *(const short8*)&B2lds[(n * 16 + l15) * 128 + ga * 8];
                acc[n] = __builtin_amdgcn_mfma_f32_16x16x32_bf16(hf[kc], bf, acc[n], 0, 0, 0);
            }
        }

        // ---- ReLU + y store + BN partials in registers ----
        #pragma unroll
        for (int n = 0; n < 8; ++n) {
            int col = n * 16 + l15;
            #pragma unroll
            for (int r = 0; r < 4; ++r) {
                int row = rowBase + quad * 4 + r;
                float v = fmaxf(acc[n][r] + bs2[n], 0.f);
                yb[row * 128 + col] = (unsigned short)f2bf(v);
                s[n] += v;
                q[n] += v * v;
            }
        }
    };

    compute(gw * 16, afA);
    if (has1) compute(g1 * 16, afB);

    // ---- flush BN partials: quad-reduce, block-reduce, one atomic set ----
    #pragma unroll
    for (int n = 0; n < 8; ++n) {
        s[n] += __shfl_xor(s[n], 16);
        s[n] += __shfl_xor(s[n], 32);
        q[n] += __shfl_xor(q[n], 16);
        q[n] += __shfl_xor(q[n], 32);
    }
    __syncthreads();  // all waves done with B1lds; reuse as scratch
    float* red = (float*)B1lds;  // [0..511]=sums [512..1023]=sqs
    if (lane < 16) {
        #pragma unroll
        for (int n = 0; n < 8; ++n) {
            red[wid * 128 + n * 16 + lane] = s[n];
            red[512 + wid * 128 + n * 16 + lane] = q[n];
        }
    }
    __syncthreads();
    float* myStats = stats + (blockIdx.x & (NREP - 1)) * 256;
    if (tid < 128) {
        float ss = 0.f, qq = 0.f;
        #pragma unroll
        for (int w = 0; w < 4; ++w) {
            ss += red[w * 128 + tid];
            qq += red[512 + w * 128 + tid];
        }
        atomicAdd(&myStats[tid], ss);
        atomicAdd(&myStats[128 + tid], qq);
    }
}

// ---------------------------------------------------------------------------
// BatchNorm apply: reduce the NREP stats replicas in-block, precompute
// per-column scale/shift, then o = y*scale + shift. 4 uint4s per thread.
// ---------------------------------------------------------------------------
__global__ __launch_bounds__(256) void bn_kernel(const uint4* __restrict__ yb4,
                                                 float* __restrict__ out,
                                                 const float* __restrict__ stats,
                                                 const float* __restrict__ gamma,
                                                 const float* __restrict__ beta)
{
    __shared__ float red[256];
    __shared__ float sc[128], sh[128];
    int tid = threadIdx.x;

    float acc = 0.f;
    #pragma unroll
    for (int r = 0; r < NREP; ++r) acc += stats[r * 256 + tid];
    red[tid] = acc;
    __syncthreads();
    if (tid < 128) {
        const float inv_n = 1.0f / (float)N_NODES;
        float m = red[tid] * inv_n;
        float var = red[128 + tid] * inv_n - m * m;
        float scale = gamma[tid] * rsqrtf(var + BN_EPS);
        sc[tid] = scale;
        sh[tid] = beta[tid] - m * scale;
    }
    __syncthreads();

    const int n8 = N_NODES * D / 8;  // 800000 uint4s
    int base = (blockIdx.x * 256 + tid) * 4;
    #pragma unroll
    for (int i = 0; i < 4; ++i) {
        int idx = base + i;
        if (idx >= n8) break;
        int c0 = (idx << 3) & 127;
        uint4 v = yb4[idx];
        float4 o0, o1;
        o0.x = bflo(v.x) * sc[c0 + 0] + sh[c0 + 0];
        o0.y = bfhi(v.x) * sc[c0 + 1] + sh[c0 + 1];
        o0.z = bflo(v.y) * sc[c0 + 2] + sh[c0 + 2];
        o0.w = bfhi(v.y) * sc[c0 + 3] + sh[c0 + 3];
        o1.x = bflo(v.z) * sc[c0 + 4] + sh[c0 + 4];
        o1.y = bfhi(v.z) * sc[c0 + 5] + sh[c0 + 5];
        o1.z = bflo(v.w) * sc[c0 + 6] + sh[c0 + 6];
        o1.w = bfhi(v.w) * sc[c0 + 7] + sh[c0 + 7];
        ((float4*)out)[idx * 2] = o0;
        ((float4*)out)[idx * 2 + 1] = o1;
    }
}

// ---------------------------------------------------------------------------
extern "C" void kernel_launch(void* const* d_in, const int* in_sizes, int n_in,
                              void* d_out, int out_size, void* d_ws, size_t ws_size,
                              hipStream_t stream) {
    const float* feature = (const float*)d_in[0];
    const int*   ei      = (const int*)d_in[1];
    const float* W1      = (const float*)d_in[2];
    const float* b1      = (const float*)d_in[3];
    const float* W2      = (const float*)d_in[4];
    const float* b2      = (const float*)d_in[5];
    const float* gamma   = (const float*)d_in[6];
    const float* beta    = (const float*)d_in[7];
    float* out = (float*)d_out;

    unsigned*       featb   = (unsigned*)d_ws;                        // 12.8 MB
    unsigned*       hb      = featb + N_NODES * 64;                   // 12.8 MB
    unsigned*       yb32    = hb + N_NODES * 64;                      // 12.8 MB
    unsigned short* Wt1     = (unsigned short*)(yb32 + N_NODES * 64); // 32 KB
    unsigned short* Wt2     = Wt1 + D * D;                            // 32 KB
    float*          stats   = (float*)(Wt2 + D * D);                  // 8 KB (NREP=8)
    int*            binCnt  = (int*)(stats + NREP * 256);             // 4 KB (zeroed w/ stats)
    unsigned*       binBuf  = (unsigned*)(binCnt + 1024);             // 3.2 MB bin runs
    unsigned short* yb      = (unsigned short*)yb32;

    prep_kernel<<<FEATC_BLOCKS + WPREP_BLOCKS + ZERO_BLOCKS, 256, 0, stream>>>(
        feature, featb, W1, W2, Wt1, Wt2, stats);
    bin_scatter_a<<<SA_BLOCKS, 256, 0, stream>>>(ei, binCnt, binBuf);
    bucket_gather<<<NBINS, 256, 0, stream>>>(
        binBuf, binCnt, (const uint4*)featb, (uint4*)hb);
    mlp_kernel<<<MLP_BLOCKS, 256, 0, stream>>>(
        (const unsigned short*)hb, Wt1, Wt2, b1, b2, yb, stats);
    bn_kernel<<<(N_NODES * D / 8 / 4 + 255) / 256, 256, 0, stream>>>(
        (const uint4*)yb, out, stats, gamma, beta);
}